// Round 1
// baseline (237.321 us; speedup 1.0000x reference)
//
#include <hip/hip_runtime.h>
#include <stdint.h>

typedef __attribute__((ext_vector_type(8))) short short8;
typedef __attribute__((ext_vector_type(4))) short short4v;
typedef __attribute__((ext_vector_type(4))) float floatx4;

#define DEV static __device__ __forceinline__

DEV unsigned short f2bf(float f) {
  union { float f; uint32_t u; } v; v.f = f;
  return (unsigned short)((v.u + 0x7FFFu + ((v.u >> 16) & 1u)) >> 16);
}
DEV float bf2f(unsigned short h) {
  union { uint32_t u; float f; } v; v.u = ((uint32_t)h) << 16;
  return v.f;
}
DEV void gload_lds16(const void* g, void* l) {
  __builtin_amdgcn_global_load_lds(
      (const __attribute__((address_space(1))) uint32_t*)g,
      (__attribute__((address_space(3))) uint32_t*)l, 16, 0, 0);
}

// ---------- fp32 -> bf16 convert: [X 4M][wq 1M][wk 1M][wv 1M][wo 1M] ----------
__global__ __launch_bounds__(256) void k_convert(
    const float* __restrict__ X, const float* __restrict__ Wq,
    const float* __restrict__ Wk, const float* __restrict__ Wv,
    const float* __restrict__ Wo, unsigned short* __restrict__ out) {
  long gid = (long)blockIdx.x * 256 + threadIdx.x;
  long e = gid * 8;
  int seg = (int)(e >> 20);
  const float* src; long base;
  if (seg < 4)      { src = X;  base = 0; }
  else if (seg == 4){ src = Wq; base = 4l << 20; }
  else if (seg == 5){ src = Wk; base = 5l << 20; }
  else if (seg == 6){ src = Wv; base = 6l << 20; }
  else              { src = Wo; base = 7l << 20; }
  const float4* s4 = (const float4*)(src + (e - base));
  float4 a = s4[0], b = s4[1];
  union { uint4 q; unsigned short s[8]; } u;
  u.s[0] = f2bf(a.x); u.s[1] = f2bf(a.y); u.s[2] = f2bf(a.z); u.s[3] = f2bf(a.w);
  u.s[4] = f2bf(b.x); u.s[5] = f2bf(b.y); u.s[6] = f2bf(b.z); u.s[7] = f2bf(b.w);
  *(uint4*)(out + e) = u.q;
}

// ---------- GEMM C = A * W^T   (A: MxK bf16 rm, W: NxK bf16 rm) ----------
// MODE 0: QKV fused (N=3072 over 3 weights), bf16 out head-major [b,h,l,64]
// MODE 1: out-proj (N=1024), f32 out row-major
template <int MODE>
__global__ __launch_bounds__(256) void k_gemm(
    const unsigned short* __restrict__ A,
    const unsigned short* __restrict__ B0, const unsigned short* __restrict__ B1,
    const unsigned short* __restrict__ B2,
    unsigned short* __restrict__ Cq, unsigned short* __restrict__ Ck,
    unsigned short* __restrict__ Cv, float* __restrict__ Cf, int K) {
  __shared__ unsigned short At[128 * 64];
  __shared__ unsigned short Bt[128 * 64];
  const int tid = threadIdx.x, lane = tid & 63, wid = tid >> 6;
  const int wm = (wid >> 1) * 64, wn = (wid & 1) * 64;
  const int g = lane >> 4, c0 = lane & 15;
  const int bm0 = blockIdx.x * 128;
  const int bnG = blockIdx.y * 128;
  const unsigned short* Bp;
  int bn0;
  if constexpr (MODE == 0) {
    int wsel = bnG >> 10;
    Bp = wsel == 0 ? B0 : (wsel == 1 ? B1 : B2);
    bn0 = bnG & 1023;
  } else { Bp = B0; bn0 = bnG; }
  floatx4 acc[4][4] = {};
  for (int kt = 0; kt < K; kt += 64) {
#pragma unroll
    for (int i = 0; i < 4; ++i) {
      int o = (wid * 64 + lane) * 16 + i * 4096;
      int row = o >> 7, k0 = (o & 127) >> 1;
      gload_lds16((const char*)A  + ((long)(bm0 + row) * K + kt + k0) * 2, (char*)At + o);
      gload_lds16((const char*)Bp + ((long)(bn0 + row) * K + kt + k0) * 2, (char*)Bt + o);
    }
    __syncthreads();
#pragma unroll
    for (int kk = 0; kk < 2; ++kk) {
      const int kb = kk * 64 + g * 16;
      short8 av[4], bv[4];
#pragma unroll
      for (int mi = 0; mi < 4; ++mi)
        av[mi] = *(const short8*)((const char*)At + (wm + mi * 16 + c0) * 128 + kb);
#pragma unroll
      for (int ni = 0; ni < 4; ++ni)
        bv[ni] = *(const short8*)((const char*)Bt + (wn + ni * 16 + c0) * 128 + kb);
#pragma unroll
      for (int mi = 0; mi < 4; ++mi)
#pragma unroll
        for (int ni = 0; ni < 4; ++ni)
          acc[mi][ni] = __builtin_amdgcn_mfma_f32_16x16x32_bf16(av[mi], bv[ni], acc[mi][ni], 0, 0, 0);
    }
    __syncthreads();
  }
#pragma unroll
  for (int mi = 0; mi < 4; ++mi)
#pragma unroll
    for (int ni = 0; ni < 4; ++ni)
#pragma unroll
      for (int i = 0; i < 4; ++i) {
        int r = bm0 + wm + mi * 16 + 4 * g + i;
        int cg = bnG + wn + ni * 16 + c0;
        float v = acc[mi][ni][i];
        if constexpr (MODE == 0) {
          int wsel = cg >> 10, cc = cg & 1023, h = cc >> 6, dkk = cc & 63;
          int bb = r >> 11, ll = r & 2047;
          unsigned short* dst = wsel == 0 ? Cq : (wsel == 1 ? Ck : Cv);
          dst[((long)(bb * 16 + h) * 2048 + ll) * 64 + dkk] = f2bf(v);
        } else {
          Cf[(long)r * 1024 + cg] = v;
        }
      }
}

// ---------- RoPE in place on [b,h,l,64] bf16; Q also scaled by log2e/8 ----------
__global__ __launch_bounds__(256) void k_rope(unsigned short* __restrict__ X, float scale) {
  int gid = blockIdx.x * 256 + threadIdx.x;  // 131072 threads: (row, half)
  int row = gid >> 1, half = gid & 1;
  int l = row & 2047;
  unsigned short* p = X + (long)row * 64 + half * 32;
  union { uint4 q[4]; unsigned short s[32]; } u;
#pragma unroll
  for (int i = 0; i < 4; ++i) u.q[i] = ((const uint4*)p)[i];
  float lf = (float)l;
#pragma unroll
  for (int j = 0; j < 16; ++j) {
    int pp = half * 16 + j;
    float ang = lf * exp2f(-(float)pp * 0.4152410118609203f);  // log2(10000)/32
    float sv, cv; sincosf(ang, &sv, &cv);
    float x1 = bf2f(u.s[2 * j]), x2 = bf2f(u.s[2 * j + 1]);
    u.s[2 * j]     = f2bf((x1 * cv - x2 * sv) * scale);
    u.s[2 * j + 1] = f2bf((x1 * sv + x2 * cv) * scale);
  }
#pragma unroll
  for (int i = 0; i < 4; ++i) ((uint4*)p)[i] = u.q[i];
}

// ---------- causal flash attention: 1 block = 64 q rows of one (b,h) ----------
__global__ __launch_bounds__(256) void k_attn(
    const unsigned short* __restrict__ Q, const unsigned short* __restrict__ K,
    const unsigned short* __restrict__ V, unsigned short* __restrict__ O) {
  __shared__ unsigned short Kt[64 * 64];      // [kv][dk] xor-swizzled slots
  __shared__ unsigned short Vt[64 * 68];      // [dv][kv] transposed, stride 68
  __shared__ unsigned short Pt[4 * 16 * 68];  // per-wave P, stride 68
  const int bx = blockIdx.x;
  const int bh = bx >> 5, qt = bx & 31;
  const int tid = threadIdx.x, lane = tid & 63, wid = tid >> 6;
  const int g = lane >> 4, c0 = lane & 15;
  const long hoff = (long)bh * 2048 * 64;
  const unsigned short* Qh = Q + hoff;
  const char* Kb = (const char*)(K + hoff);
  const unsigned short* Vh = V + hoff;
  const int q0 = qt * 64 + wid * 16;
  short8 qf[2];
#pragma unroll
  for (int kk = 0; kk < 2; ++kk)
    qf[kk] = *(const short8*)(Qh + (long)(q0 + c0) * 64 + kk * 32 + g * 8);
  floatx4 ctx[4] = {};
  float m_[4], l_[4];
#pragma unroll
  for (int i = 0; i < 4; ++i) { m_[i] = -1e30f; l_[i] = 0.f; }
  unsigned short* Pw = Pt + wid * (16 * 68);

  for (int kvt = 0; kvt <= qt; ++kvt) {
    // stage K: linear LDS dest, XOR-swizzled global source (read-side swz matches)
#pragma unroll
    for (int i = 0; i < 2; ++i) {
      int o = (wid * 64 + lane) * 16 + i * 4096;
      int row = o >> 7;
      int src = (o & ~127) | ((o & 127) ^ ((row & 7) << 4));
      gload_lds16(Kb + (long)kvt * 8192 + src, (char*)Kt + o);
    }
    // stage V transposed: Vt[dv][kv]
#pragma unroll
    for (int pz = 0; pz < 2; ++pz) {
      int idx = tid + 256 * pz;
      int kv = idx >> 3, dv0 = (idx & 7) * 8;
      union { uint4 q; unsigned short s[8]; } u;
      u.q = *(const uint4*)(Vh + (long)kvt * 4096 + idx * 8);
#pragma unroll
      for (int j = 0; j < 8; ++j) Vt[(dv0 + j) * 68 + kv] = u.s[j];
    }
    __syncthreads();

    // S = Q K^T (pre-scaled by log2e/8 via Q)
    floatx4 s[4] = {};
#pragma unroll
    for (int t = 0; t < 4; ++t) {
      int rowk = t * 16 + c0;
#pragma unroll
      for (int kk = 0; kk < 2; ++kk) {
        short8 kfr = *(const short8*)((const char*)Kt + rowk * 128 +
                                      ((kk * 64 + g * 16) ^ ((rowk & 7) << 4)));
        s[t] = __builtin_amdgcn_mfma_f32_16x16x32_bf16(qf[kk], kfr, s[t], 0, 0, 0);
      }
    }
    if (kvt == qt) {
#pragma unroll
      for (int t = 0; t < 4; ++t)
#pragma unroll
        for (int i = 0; i < 4; ++i)
          if (qt * 64 + t * 16 + c0 > q0 + 4 * g + i) s[t][i] = -1e30f;
    }
    // online softmax (rows = 4g+i, reduce over c0 within 16-lane group)
    float sc[4];
#pragma unroll
    for (int i = 0; i < 4; ++i) {
      float mx = fmaxf(fmaxf(s[0][i], s[1][i]), fmaxf(s[2][i], s[3][i]));
      mx = fmaxf(mx, __shfl_xor(mx, 1));
      mx = fmaxf(mx, __shfl_xor(mx, 2));
      mx = fmaxf(mx, __shfl_xor(mx, 4));
      mx = fmaxf(mx, __shfl_xor(mx, 8));
      float mn = fmaxf(m_[i], mx);
      sc[i] = exp2f(m_[i] - mn);
      m_[i] = mn;
    }
#pragma unroll
    for (int t = 0; t < 4; ++t)
#pragma unroll
      for (int i = 0; i < 4; ++i)
        s[t][i] = exp2f(s[t][i] - m_[i]);
#pragma unroll
    for (int i = 0; i < 4; ++i) {
      float r = s[0][i] + s[1][i] + s[2][i] + s[3][i];
      r += __shfl_xor(r, 1); r += __shfl_xor(r, 2);
      r += __shfl_xor(r, 4); r += __shfl_xor(r, 8);
      l_[i] = l_[i] * sc[i] + r;
#pragma unroll
      for (int n = 0; n < 4; ++n) ctx[n][i] *= sc[i];
    }
    // P -> per-wave LDS (C-layout write, A-layout read)
#pragma unroll
    for (int t = 0; t < 4; ++t)
#pragma unroll
      for (int i = 0; i < 4; ++i)
        Pw[(4 * g + i) * 68 + t * 16 + c0] = f2bf(s[t][i]);
    short8 pa[2];
#pragma unroll
    for (int kk = 0; kk < 2; ++kk) {
      const char* pb = (const char*)(Pw + c0 * 68) + kk * 64 + g * 16;
      short4v plo = *(const short4v*)pb;
      short4v phi = *(const short4v*)(pb + 8);
      pa[kk] = __builtin_shufflevector(plo, phi, 0, 1, 2, 3, 4, 5, 6, 7);
    }
#pragma unroll
    for (int n = 0; n < 4; ++n) {
#pragma unroll
      for (int kk = 0; kk < 2; ++kk) {
        const char* vb = (const char*)(Vt + (n * 16 + c0) * 68) + kk * 64 + g * 16;
        short4v vlo = *(const short4v*)vb;
        short4v vhi = *(const short4v*)(vb + 8);
        short8 vfr = __builtin_shufflevector(vlo, vhi, 0, 1, 2, 3, 4, 5, 6, 7);
        ctx[n] = __builtin_amdgcn_mfma_f32_16x16x32_bf16(pa[kk], vfr, ctx[n], 0, 0, 0);
      }
    }
    __syncthreads();
  }
  // epilogue: ctx/l -> bf16 [b, l, h*64+dv]
  const int b = bh >> 4, h = bh & 15;
#pragma unroll
  for (int i = 0; i < 4; ++i) {
    float inv = 1.f / l_[i];
    long rowb = (long)(b * 2048 + q0 + 4 * g + i) * 1024 + h * 64;
#pragma unroll
    for (int n = 0; n < 4; ++n)
      O[rowb + n * 16 + c0] = f2bf(ctx[n][i] * inv);
  }
}

extern "C" void kernel_launch(void* const* d_in, const int* in_sizes, int n_in,
                              void* d_out, int out_size, void* d_ws, size_t ws_size,
                              hipStream_t stream) {
  const float* X  = (const float*)d_in[0];
  const float* Wq = (const float*)d_in[1];
  const float* Wk = (const float*)d_in[2];
  const float* Wv = (const float*)d_in[3];
  const float* Wo = (const float*)d_in[4];
  unsigned short* Xb  = (unsigned short*)d_ws;   // 4M elems
  unsigned short* Wqb = Xb + (4l << 20);
  unsigned short* Wkb = Xb + (5l << 20);
  unsigned short* Wvb = Xb + (6l << 20);
  unsigned short* Wob = Xb + (7l << 20);
  unsigned short* Qw  = Xb + (8l << 20);         // [2,16,2048,64]
  unsigned short* Kw  = Xb + (12l << 20);
  unsigned short* Vw  = Xb + (16l << 20);
  unsigned short* Cw  = Xb + (20l << 20);        // ctx [b,l,1024]
  float* Out = (float*)d_out;

  k_convert<<<4096, 256, 0, stream>>>(X, Wq, Wk, Wv, Wo, Xb);
  k_gemm<0><<<dim3(32, 24), 256, 0, stream>>>(Xb, Wqb, Wkb, Wvb, Qw, Kw, Vw, nullptr, 1024);
  k_rope<<<512, 256, 0, stream>>>(Qw, 0.18033688011112042f);  // log2(e)/8
  k_rope<<<512, 256, 0, stream>>>(Kw, 1.0f);
  k_attn<<<1024, 256, 0, stream>>>(Qw, Kw, Vw, Cw);
  k_gemm<1><<<dim3(32, 8), 256, 0, stream>>>(Cw, Wob, nullptr, nullptr,
                                             nullptr, nullptr, nullptr, Out, 1024);
}

// Round 2
// 218.058 us; speedup vs baseline: 1.0883x; 1.0883x over previous
//
#include <hip/hip_runtime.h>
#include <stdint.h>

typedef __attribute__((ext_vector_type(8))) short short8;
typedef __attribute__((ext_vector_type(4))) short short4v;
typedef __attribute__((ext_vector_type(4))) float floatx4;

#define DEV static __device__ __forceinline__

DEV unsigned short f2bf(float f) {
  union { float f; uint32_t u; } v; v.f = f;
  return (unsigned short)((v.u + 0x7FFFu + ((v.u >> 16) & 1u)) >> 16);
}
DEV float bf2f(unsigned short h) {
  union { uint32_t u; float f; } v; v.u = ((uint32_t)h) << 16;
  return v.f;
}
DEV void gload_lds16(const void* g, void* l) {
  __builtin_amdgcn_global_load_lds(
      (const __attribute__((address_space(1))) uint32_t*)g,
      (__attribute__((address_space(3))) uint32_t*)l, 16, 0, 0);
}

// ---------- fp32 -> bf16 convert: [X 4M][wq 1M][wk 1M][wv 1M][wo 1M] ----------
__global__ __launch_bounds__(256) void k_convert(
    const float* __restrict__ X, const float* __restrict__ Wq,
    const float* __restrict__ Wk, const float* __restrict__ Wv,
    const float* __restrict__ Wo, unsigned short* __restrict__ out) {
  long gid = (long)blockIdx.x * 256 + threadIdx.x;
  long e = gid * 8;
  int seg = (int)(e >> 20);
  const float* src; long base;
  if (seg < 4)      { src = X;  base = 0; }
  else if (seg == 4){ src = Wq; base = 4l << 20; }
  else if (seg == 5){ src = Wk; base = 5l << 20; }
  else if (seg == 6){ src = Wv; base = 6l << 20; }
  else              { src = Wo; base = 7l << 20; }
  const float4* s4 = (const float4*)(src + (e - base));
  float4 a = s4[0], b = s4[1];
  union { uint4 q; unsigned short s[8]; } u;
  u.s[0] = f2bf(a.x); u.s[1] = f2bf(a.y); u.s[2] = f2bf(a.z); u.s[3] = f2bf(a.w);
  u.s[4] = f2bf(b.x); u.s[5] = f2bf(b.y); u.s[6] = f2bf(b.z); u.s[7] = f2bf(b.w);
  *(uint4*)(out + e) = u.q;
}

// ---------- GEMM C = A * W^T   (A: MxK bf16 rm, W: NxK bf16 rm) ----------
template <int MODE>
__global__ __launch_bounds__(256) void k_gemm(
    const unsigned short* __restrict__ A,
    const unsigned short* __restrict__ B0, const unsigned short* __restrict__ B1,
    const unsigned short* __restrict__ B2,
    unsigned short* __restrict__ Cq, unsigned short* __restrict__ Ck,
    unsigned short* __restrict__ Cv, float* __restrict__ Cf, int K) {
  __shared__ unsigned short At[128 * 64];
  __shared__ unsigned short Bt[128 * 64];
  const int tid = threadIdx.x, lane = tid & 63, wid = tid >> 6;
  const int wm = (wid >> 1) * 64, wn = (wid & 1) * 64;
  const int g = lane >> 4, c0 = lane & 15;
  const int bm0 = blockIdx.x * 128;
  const int bnG = blockIdx.y * 128;
  const unsigned short* Bp;
  int bn0;
  if constexpr (MODE == 0) {
    int wsel = bnG >> 10;
    Bp = wsel == 0 ? B0 : (wsel == 1 ? B1 : B2);
    bn0 = bnG & 1023;
  } else { Bp = B0; bn0 = bnG; }
  floatx4 acc[4][4] = {};
  for (int kt = 0; kt < K; kt += 64) {
#pragma unroll
    for (int i = 0; i < 4; ++i) {
      int o = (wid * 64 + lane) * 16 + i * 4096;
      int row = o >> 7, k0 = (o & 127) >> 1;
      gload_lds16((const char*)A  + ((long)(bm0 + row) * K + kt + k0) * 2, (char*)At + o);
      gload_lds16((const char*)Bp + ((long)(bn0 + row) * K + kt + k0) * 2, (char*)Bt + o);
    }
    __syncthreads();
#pragma unroll
    for (int kk = 0; kk < 2; ++kk) {
      const int kb = kk * 64 + g * 16;
      short8 av[4], bv[4];
#pragma unroll
      for (int mi = 0; mi < 4; ++mi)
        av[mi] = *(const short8*)((const char*)At + (wm + mi * 16 + c0) * 128 + kb);
#pragma unroll
      for (int ni = 0; ni < 4; ++ni)
        bv[ni] = *(const short8*)((const char*)Bt + (wn + ni * 16 + c0) * 128 + kb);
#pragma unroll
      for (int mi = 0; mi < 4; ++mi)
#pragma unroll
        for (int ni = 0; ni < 4; ++ni)
          acc[mi][ni] = __builtin_amdgcn_mfma_f32_16x16x32_bf16(av[mi], bv[ni], acc[mi][ni], 0, 0, 0);
    }
    __syncthreads();
  }
#pragma unroll
  for (int mi = 0; mi < 4; ++mi)
#pragma unroll
    for (int ni = 0; ni < 4; ++ni)
#pragma unroll
      for (int i = 0; i < 4; ++i) {
        int r = bm0 + wm + mi * 16 + 4 * g + i;
        int cg = bnG + wn + ni * 16 + c0;
        float v = acc[mi][ni][i];
        if constexpr (MODE == 0) {
          int wsel = cg >> 10, cc = cg & 1023, h = cc >> 6, dkk = cc & 63;
          int bb = r >> 11, ll = r & 2047;
          unsigned short* dst = wsel == 0 ? Cq : (wsel == 1 ? Ck : Cv);
          dst[((long)(bb * 16 + h) * 2048 + ll) * 64 + dkk] = f2bf(v);
        } else {
          Cf[(long)r * 1024 + cg] = v;
        }
      }
}

// ---------- RoPE in place on Q||K (contiguous, each [2,16,2048,64] bf16) ----------
__global__ __launch_bounds__(256) void k_rope(unsigned short* __restrict__ QK, float qscale) {
  int gid = blockIdx.x * 256 + threadIdx.x;  // 262144 threads: (row, half)
  int row = gid >> 1, hf = gid & 1;          // rows 0..65535 = Q, rest = K
  float scale = row < 65536 ? qscale : 1.0f;
  int l = row & 2047;
  unsigned short* p = QK + (long)row * 64 + hf * 32;
  union { uint4 q[4]; unsigned short s[32]; } u;
#pragma unroll
  for (int i = 0; i < 4; ++i) u.q[i] = ((const uint4*)p)[i];
  float lf = (float)l;
#pragma unroll
  for (int j = 0; j < 16; ++j) {
    int pp = hf * 16 + j;
    float ang = lf * exp2f(-(float)pp * 0.4152410118609203f);  // log2(10000)/32
    float sv, cv; sincosf(ang, &sv, &cv);
    float x1 = bf2f(u.s[2 * j]), x2 = bf2f(u.s[2 * j + 1]);
    u.s[2 * j]     = f2bf((x1 * cv - x2 * sv) * scale);
    u.s[2 * j + 1] = f2bf((x1 * sv + x2 * cv) * scale);
  }
#pragma unroll
  for (int i = 0; i < 4; ++i) ((uint4*)p)[i] = u.q[i];
}

// ---------- V [bh, 2048, 64] -> V^T [bh, 64, 2048] ----------
__global__ __launch_bounds__(256) void k_transpose(
    const unsigned short* __restrict__ in, unsigned short* __restrict__ out) {
  __shared__ unsigned short t[64][68];
  const int bh = blockIdx.x >> 5, lt = blockIdx.x & 31;
  const int tid = threadIdx.x;
  const unsigned short* src = in + ((long)bh * 2048 + lt * 64) * 64;
#pragma unroll
  for (int p = 0; p < 2; ++p) {
    int idx = tid + p * 256;
    int row = idx >> 3, c = (idx & 7) * 8;
    union { uint4 q; unsigned short s[8]; } u;
    u.q = *(const uint4*)(src + row * 64 + c);
#pragma unroll
    for (int j = 0; j < 8; ++j) t[row][c + j] = u.s[j];
  }
  __syncthreads();
  unsigned short* dst = out + (long)bh * 64 * 2048 + lt * 64;
#pragma unroll
  for (int p = 0; p < 2; ++p) {
    int idx = tid + p * 256;
    int dv = idx >> 3, lc = (idx & 7) * 8;
    union { uint4 q; unsigned short s[8]; } u;
#pragma unroll
    for (int j = 0; j < 8; ++j) u.s[j] = t[lc + j][dv];
    *(uint4*)(dst + (long)dv * 2048 + lc) = u.q;
  }
}

// ---------- causal flash attention: wave-independent, no K/V LDS ----------
DEV void attn_body(int T, int qt, int q0, int g, int c0,
                   const unsigned short* __restrict__ Kh,
                   const unsigned short* __restrict__ Vh,
                   unsigned short* Pw, const short8 (&qf)[2],
                   short8 (&KF)[4][2], short8 (&KFO)[4][2],
                   floatx4 (&ctx)[4], float (&m_)[4], float (&l_)[4]) {
  // V^T fragments for this tile
  short8 vf[4][2];
  {
    const unsigned short* vp = Vh + (long)c0 * 2048 + T * 64 + g * 8;
#pragma unroll
    for (int n = 0; n < 4; ++n)
#pragma unroll
      for (int kk = 0; kk < 2; ++kk)
        vf[n][kk] = *(const short8*)(vp + n * 32768 + kk * 32);
  }
  // prefetch next K tile into the other register buffer
  if (T < qt) {
    const unsigned short* kp = Kh + ((long)(T + 1) * 64 + c0) * 64 + g * 8;
#pragma unroll
    for (int tt = 0; tt < 4; ++tt)
#pragma unroll
      for (int kk = 0; kk < 2; ++kk)
        KFO[tt][kk] = *(const short8*)(kp + tt * 1024 + kk * 32);
  }
  // S = Q K^T (Q pre-scaled by log2e/8)
  floatx4 s[4] = {};
#pragma unroll
  for (int tt = 0; tt < 4; ++tt)
#pragma unroll
    for (int kk = 0; kk < 2; ++kk)
      s[tt] = __builtin_amdgcn_mfma_f32_16x16x32_bf16(qf[kk], KF[tt][kk], s[tt], 0, 0, 0);
  if (T == qt) {
#pragma unroll
    for (int tt = 0; tt < 4; ++tt)
#pragma unroll
      for (int i = 0; i < 4; ++i)
        if (T * 64 + tt * 16 + c0 > q0 + 4 * g + i) s[tt][i] = -1e30f;
  }
  // online softmax: rows 4g+i, reduce across c0 (16-lane groups)
  float sc_[4];
#pragma unroll
  for (int i = 0; i < 4; ++i) {
    float mx = fmaxf(fmaxf(s[0][i], s[1][i]), fmaxf(s[2][i], s[3][i]));
    mx = fmaxf(mx, __shfl_xor(mx, 1));
    mx = fmaxf(mx, __shfl_xor(mx, 2));
    mx = fmaxf(mx, __shfl_xor(mx, 4));
    mx = fmaxf(mx, __shfl_xor(mx, 8));
    float mn = fmaxf(m_[i], mx);
    sc_[i] = exp2f(m_[i] - mn);
    m_[i] = mn;
  }
#pragma unroll
  for (int tt = 0; tt < 4; ++tt)
#pragma unroll
    for (int i = 0; i < 4; ++i)
      s[tt][i] = exp2f(s[tt][i] - m_[i]);
#pragma unroll
  for (int i = 0; i < 4; ++i) {
    float r = s[0][i] + s[1][i] + s[2][i] + s[3][i];
    r += __shfl_xor(r, 1); r += __shfl_xor(r, 2);
    r += __shfl_xor(r, 4); r += __shfl_xor(r, 8);
    l_[i] = l_[i] * sc_[i] + r;
#pragma unroll
    for (int n = 0; n < 4; ++n) ctx[n][i] *= sc_[i];
  }
  // P: C-layout -> LDS -> A-layout (per-wave private buffer)
#pragma unroll
  for (int tt = 0; tt < 4; ++tt)
#pragma unroll
    for (int i = 0; i < 4; ++i)
      Pw[(4 * g + i) * 68 + tt * 16 + c0] = f2bf(s[tt][i]);
  short8 pa[2];
#pragma unroll
  for (int kk = 0; kk < 2; ++kk) {
    const char* pb = (const char*)(Pw + c0 * 68) + kk * 64 + g * 16;
    short4v plo = *(const short4v*)pb;
    short4v phi = *(const short4v*)(pb + 8);
    pa[kk] = __builtin_shufflevector(plo, phi, 0, 1, 2, 3, 4, 5, 6, 7);
  }
#pragma unroll
  for (int n = 0; n < 4; ++n)
#pragma unroll
    for (int kk = 0; kk < 2; ++kk)
      ctx[n] = __builtin_amdgcn_mfma_f32_16x16x32_bf16(pa[kk], vf[n][kk], ctx[n], 0, 0, 0);
}

__global__ __launch_bounds__(256) void k_attn(
    const unsigned short* __restrict__ Q, const unsigned short* __restrict__ K,
    const unsigned short* __restrict__ Vt, unsigned short* __restrict__ O) {
  __shared__ unsigned short Pt[4][16 * 68];
  const int bid = blockIdx.x;
  const int wg = (bid & 7) * 64 + (bid >> 3);  // XCD swizzle (512 = 8*64, bijective)
  const int bh = wg >> 4, pr = wg & 15;        // 4 heads per XCD -> KV L2-resident
  const int tid = threadIdx.x, lane = tid & 63, wid = tid >> 6;
  const int g = lane >> 4, c0 = lane & 15;
  const long hoff = (long)bh * 2048 * 64;
  const unsigned short* Qh = Q + hoff;
  const unsigned short* Kh = K + hoff;
  const unsigned short* Vh = Vt + hoff;  // [64][2048]
  unsigned short* Pw = Pt[wid];
  const int b = bh >> 4, h = bh & 15;

  // paired q-tiles (pr, 31-pr): every block does exactly 33 KV-tile iterations
#pragma unroll 1
  for (int hh = 0; hh < 2; ++hh) {
    const int qt = hh ? (31 - pr) : pr;
    const int q0 = qt * 64 + wid * 16;
    short8 qf[2];
#pragma unroll
    for (int kk = 0; kk < 2; ++kk)
      qf[kk] = *(const short8*)(Qh + (long)(q0 + c0) * 64 + kk * 32 + g * 8);
    floatx4 ctx[4] = {};
    float m_[4], l_[4];
#pragma unroll
    for (int i = 0; i < 4; ++i) { m_[i] = -1e30f; l_[i] = 0.f; }
    short8 kfA[4][2], kfB[4][2];
    {
      const unsigned short* kp = Kh + (long)c0 * 64 + g * 8;
#pragma unroll
      for (int tt = 0; tt < 4; ++tt)
#pragma unroll
        for (int kk = 0; kk < 2; ++kk)
          kfA[tt][kk] = *(const short8*)(kp + tt * 1024 + kk * 32);
    }
    int t = 0;
    while (true) {
      attn_body(t, qt, q0, g, c0, Kh, Vh, Pw, qf, kfA, kfB, ctx, m_, l_);
      if (++t > qt) break;
      attn_body(t, qt, q0, g, c0, Kh, Vh, Pw, qf, kfB, kfA, ctx, m_, l_);
      if (++t > qt) break;
    }
    // epilogue: ctx/l -> bf16 ctx buffer [b, l, h*64+dv]
#pragma unroll
    for (int i = 0; i < 4; ++i) {
      float inv = 1.f / l_[i];
      long rowb = (long)(b * 2048 + q0 + 4 * g + i) * 1024 + h * 64;
#pragma unroll
      for (int n = 0; n < 4; ++n)
        O[rowb + n * 16 + c0] = f2bf(ctx[n][i] * inv);
    }
  }
}

extern "C" void kernel_launch(void* const* d_in, const int* in_sizes, int n_in,
                              void* d_out, int out_size, void* d_ws, size_t ws_size,
                              hipStream_t stream) {
  const float* X  = (const float*)d_in[0];
  const float* Wq = (const float*)d_in[1];
  const float* Wk = (const float*)d_in[2];
  const float* Wv = (const float*)d_in[3];
  const float* Wo = (const float*)d_in[4];
  unsigned short* Xb  = (unsigned short*)d_ws;   // 4M elems (bf16 X; reused as V^T later)
  unsigned short* Wqb = Xb + (4l << 20);
  unsigned short* Wkb = Xb + (5l << 20);
  unsigned short* Wvb = Xb + (6l << 20);
  unsigned short* Wob = Xb + (7l << 20);
  unsigned short* Qw  = Xb + (8l << 20);         // [2,16,2048,64]
  unsigned short* Kw  = Xb + (12l << 20);
  unsigned short* Vw  = Xb + (16l << 20);
  unsigned short* Vtw = Xb;                      // alias: X-bf16 dead after QKV GEMM
  unsigned short* Cw  = Xb + (20l << 20);        // ctx [b,l,1024]
  float* Out = (float*)d_out;

  k_convert<<<4096, 256, 0, stream>>>(X, Wq, Wk, Wv, Wo, Xb);
  k_gemm<0><<<dim3(32, 24), 256, 0, stream>>>(Xb, Wqb, Wkb, Wvb, Qw, Kw, Vw, nullptr, 1024);
  k_rope<<<1024, 256, 0, stream>>>(Qw, 0.18033688011112042f);  // log2(e)/8
  k_transpose<<<1024, 256, 0, stream>>>(Vw, Vtw);
  k_attn<<<512, 256, 0, stream>>>(Qw, Kw, Vtw, Cw);
  k_gemm<1><<<dim3(32, 8), 256, 0, stream>>>(Cw, Wob, nullptr, nullptr,
                                             nullptr, nullptr, nullptr, Out, 1024);
}